// Round 1
// baseline (4676.142 us; speedup 1.0000x reference)
//
#include <hip/hip_runtime.h>

#define N_FIN 128
#define N_HID 16
#define N_OUT 12

// ---------------- degree (in-edges; +1 self-loop added in dinv) ----------------
__global__ __launch_bounds__(256) void k_deg(const int* __restrict__ dst,
                                             unsigned* __restrict__ deg, int E) {
  int t = blockIdx.x * 256 + threadIdx.x;
  if (t < E) atomicAdd(&deg[dst[t]], 1u);
}

__global__ __launch_bounds__(256) void k_dinv(const unsigned* __restrict__ deg,
                                              float* __restrict__ dinv, int N) {
  int t = blockIdx.x * 256 + threadIdx.x;
  if (t < N) dinv[t] = rsqrtf((float)(deg[t] + 1u));
}

// ---------------- hs = dinv * (x @ W1), x:[N,128] W1:[128,16] ----------------
// 16 rows/block, thread=(row,col) with 16 threads per row. x tile + W1^T in LDS.
__global__ __launch_bounds__(256) void k_gemm1(const float* __restrict__ x,
                                               const float* __restrict__ W1,
                                               const float* __restrict__ dinv,
                                               float* __restrict__ hs, int N) {
  __shared__ float xs[16][132];   // pad 132: rows land on distinct banks
  __shared__ float wT[16][132];   // wT[col][k]
  int t = threadIdx.x;
  // stage W1 transposed (coalesced read, 2-way-conflict LDS write = free)
#pragma unroll
  for (int i = 0; i < 8; ++i) {
    int idx = t + i * 256;        // 0..2047
    int k = idx >> 4, c = idx & 15;
    wT[c][k] = W1[idx];
  }
  int row0 = blockIdx.x * 16;
  // stage 16 rows of x as float4 (fully coalesced)
#pragma unroll
  for (int i = 0; i < 2; ++i) {
    int idx = t + i * 256;        // 0..511
    int r = idx >> 5, c4 = idx & 31;
    float4 v = make_float4(0.f, 0.f, 0.f, 0.f);
    if (row0 + r < N) v = *(const float4*)(x + (size_t)(row0 + r) * N_FIN + c4 * 4);
    *(float4*)&xs[r][c4 * 4] = v;
  }
  __syncthreads();
  int col = t & 15, r = t >> 4;
  float acc = 0.f;
#pragma unroll
  for (int kc = 0; kc < 32; ++kc) {
    float4 xv = *(const float4*)&xs[r][kc * 4];
    float4 wv = *(const float4*)&wT[col][kc * 4];
    acc += xv.x * wv.x + xv.y * wv.y + xv.z * wv.z + xv.w * wv.w;
  }
  int row = row0 + r;
  if (row < N) hs[(size_t)row * N_HID + col] = dinv[row] * acc;
}

// ---------------- edge aggregation: agg[d] += h[s]  (NQ float4 per node) ------
template <int NQ>
__global__ __launch_bounds__(256) void k_agg(const int* __restrict__ src,
                                             const int* __restrict__ dst,
                                             const float* __restrict__ h,
                                             float* __restrict__ agg, int E) {
  int t = blockIdx.x * 256 + threadIdx.x;
  if (t >= E) return;
  int s = src[t], d = dst[t];
  const float4* hv = (const float4*)(h + (size_t)s * (NQ * 4));
  float* a = agg + (size_t)d * (NQ * 4);
#pragma unroll
  for (int q = 0; q < NQ; ++q) {
    float4 v = hv[q];
    atomicAdd(a + q * 4 + 0, v.x);
    atomicAdd(a + q * 4 + 1, v.y);
    atomicAdd(a + q * 4 + 2, v.z);
    atomicAdd(a + q * 4 + 3, v.w);
  }
}

// ------- finalize layer1 (+self-loop, bias, relu) fused with 16->12 GEMM ------
__global__ __launch_bounds__(256) void k_fin1(const float* __restrict__ agg1,
                                              const float* __restrict__ hs,
                                              const float* __restrict__ dinv,
                                              const float* __restrict__ b1,
                                              const float* __restrict__ W2,
                                              float* __restrict__ hs2, int N) {
  __shared__ float w2s[N_HID * N_OUT];
  __shared__ float b1s[N_HID];
  int t = threadIdx.x;
  if (t < N_HID * N_OUT) w2s[t] = W2[t];
  if (t < N_HID) b1s[t] = b1[t];
  __syncthreads();
  int i = blockIdx.x * 256 + t;
  if (i >= N) return;
  float di = dinv[i];
  float o[N_HID];
#pragma unroll
  for (int q = 0; q < 4; ++q) {
    float4 av = *(const float4*)(agg1 + (size_t)i * N_HID + q * 4);
    float4 hv = *(const float4*)(hs + (size_t)i * N_HID + q * 4);
    o[q * 4 + 0] = fmaxf(di * (av.x + hv.x) + b1s[q * 4 + 0], 0.f);
    o[q * 4 + 1] = fmaxf(di * (av.y + hv.y) + b1s[q * 4 + 1], 0.f);
    o[q * 4 + 2] = fmaxf(di * (av.z + hv.z) + b1s[q * 4 + 2], 0.f);
    o[q * 4 + 3] = fmaxf(di * (av.w + hv.w) + b1s[q * 4 + 3], 0.f);
  }
  float h2[N_OUT];
#pragma unroll
  for (int j = 0; j < N_OUT; ++j) {
    float s = 0.f;
#pragma unroll
    for (int c = 0; c < N_HID; ++c) s += o[c] * w2s[c * N_OUT + j];
    h2[j] = s;
  }
#pragma unroll
  for (int q = 0; q < 3; ++q) {
    float4 v = make_float4(di * h2[q * 4 + 0], di * h2[q * 4 + 1],
                           di * h2[q * 4 + 2], di * h2[q * 4 + 3]);
    *(float4*)(hs2 + (size_t)i * N_OUT + q * 4) = v;
  }
}

// ------------- finalize layer2 (+self-loop, bias) + log_softmax ---------------
__global__ __launch_bounds__(256) void k_fin2(const float* __restrict__ agg2,
                                              const float* __restrict__ hs2,
                                              const float* __restrict__ dinv,
                                              const float* __restrict__ b2,
                                              float* __restrict__ out, int N) {
  __shared__ float b2s[N_OUT];
  int t = threadIdx.x;
  if (t < N_OUT) b2s[t] = b2[t];
  __syncthreads();
  int i = blockIdx.x * 256 + t;
  if (i >= N) return;
  float di = dinv[i];
  float z[N_OUT];
#pragma unroll
  for (int q = 0; q < 3; ++q) {
    float4 av = *(const float4*)(agg2 + (size_t)i * N_OUT + q * 4);
    float4 hv = *(const float4*)(hs2 + (size_t)i * N_OUT + q * 4);
    z[q * 4 + 0] = di * (av.x + hv.x) + b2s[q * 4 + 0];
    z[q * 4 + 1] = di * (av.y + hv.y) + b2s[q * 4 + 1];
    z[q * 4 + 2] = di * (av.z + hv.z) + b2s[q * 4 + 2];
    z[q * 4 + 3] = di * (av.w + hv.w) + b2s[q * 4 + 3];
  }
  float m = z[0];
#pragma unroll
  for (int j = 1; j < N_OUT; ++j) m = fmaxf(m, z[j]);
  float sum = 0.f;
#pragma unroll
  for (int j = 0; j < N_OUT; ++j) sum += __expf(z[j] - m);
  float l = m + __logf(sum);
#pragma unroll
  for (int q = 0; q < 3; ++q) {
    float4 v = make_float4(z[q * 4 + 0] - l, z[q * 4 + 1] - l,
                           z[q * 4 + 2] - l, z[q * 4 + 3] - l);
    *(float4*)(out + (size_t)i * N_OUT + q * 4) = v;
  }
}

extern "C" void kernel_launch(void* const* d_in, const int* in_sizes, int n_in,
                              void* d_out, int out_size, void* d_ws, size_t ws_size,
                              hipStream_t stream) {
  const float* x  = (const float*)d_in[0];
  const int*   ei = (const int*)d_in[1];
  const float* W1 = (const float*)d_in[2];
  const float* b1 = (const float*)d_in[3];
  const float* W2 = (const float*)d_in[4];
  const float* b2 = (const float*)d_in[5];
  int N = in_sizes[0] / N_FIN;
  int E = in_sizes[1] / 2;
  const int* src = ei;
  const int* dst = ei + E;

  // workspace layout: [deg u32 N][agg1 f32 N*16][agg2 f32 N*12] | [dinv N][hs N*16][hs2 N*12]
  char* ws = (char*)d_ws;
  unsigned* deg = (unsigned*)ws;
  float* agg1 = (float*)(ws + (size_t)N * 4);
  float* agg2 = (float*)(ws + (size_t)N * 4 + (size_t)N * 64);
  float* dinv = (float*)(ws + (size_t)N * 4 + (size_t)N * 64 + (size_t)N * 48);
  float* hs   = dinv + N;
  float* hs2  = hs + (size_t)N * N_HID;
  size_t zbytes = (size_t)N * (4 + 64 + 48);
  hipMemsetAsync(d_ws, 0, zbytes, stream);

  k_deg<<<(E + 255) / 256, 256, 0, stream>>>(dst, deg, E);
  k_dinv<<<(N + 255) / 256, 256, 0, stream>>>(deg, dinv, N);
  k_gemm1<<<(N + 15) / 16, 256, 0, stream>>>(x, W1, dinv, hs, N);
  k_agg<4><<<(E + 255) / 256, 256, 0, stream>>>(src, dst, hs, agg1, E);
  k_fin1<<<(N + 255) / 256, 256, 0, stream>>>(agg1, hs, dinv, b1, W2, hs2, N);
  k_agg<3><<<(E + 255) / 256, 256, 0, stream>>>(src, dst, hs2, agg2, E);
  k_fin2<<<(N + 255) / 256, 256, 0, stream>>>(agg2, hs2, dinv, b2, (float*)d_out, N);
}

// Round 2
// 666.953 us; speedup vs baseline: 7.0112x; 7.0112x over previous
//
#include <hip/hip_runtime.h>

#define N_FIN 128
#define N_HID 16
#define N_OUT 12

// ---------------- degree (in-edges; +1 self-loop added in dinv) ----------------
__global__ __launch_bounds__(256) void k_deg(const int* __restrict__ dst,
                                             unsigned* __restrict__ deg, int E) {
  int t = blockIdx.x * 256 + threadIdx.x;
  if (t < E) atomicAdd(&deg[dst[t]], 1u);
}

__global__ __launch_bounds__(256) void k_dinv(const unsigned* __restrict__ deg,
                                              float* __restrict__ dinv, int N) {
  int t = blockIdx.x * 256 + threadIdx.x;
  if (t < N) dinv[t] = rsqrtf((float)(deg[t] + 1u));
}

// ---------------- CSR build: exclusive scan of deg -> row_start ----------------
__global__ __launch_bounds__(256) void k_scan1(const unsigned* __restrict__ deg,
                                               unsigned* __restrict__ row_start,
                                               unsigned* __restrict__ bsum, int N) {
  __shared__ unsigned s[256];
  int t = threadIdx.x, i = blockIdx.x * 256 + t;
  unsigned v = (i < N) ? deg[i] : 0u;
  s[t] = v;
  __syncthreads();
#pragma unroll
  for (int off = 1; off < 256; off <<= 1) {
    unsigned y = (t >= off) ? s[t - off] : 0u;
    __syncthreads();
    s[t] += y;
    __syncthreads();
  }
  if (i < N) row_start[i] = s[t] - v;          // exclusive within block
  if (t == 255) bsum[blockIdx.x] = s[255];     // block total
}

__global__ void k_scan2(unsigned* __restrict__ bsum, int nb) {
  if (threadIdx.x == 0) {
    unsigned acc = 0;
    for (int i = 0; i < nb; ++i) { unsigned v = bsum[i]; bsum[i] = acc; acc += v; }
  }
}

__global__ __launch_bounds__(256) void k_scan3(unsigned* __restrict__ row_start,
                                               const unsigned* __restrict__ bsum,
                                               unsigned* __restrict__ cursor, int N) {
  int i = blockIdx.x * 256 + threadIdx.x;
  if (i < N) {
    unsigned r = row_start[i] + bsum[blockIdx.x];
    row_start[i] = r;
    cursor[i] = r;
  }
}

// scatter edges into CSR order (3.2M int atomics — cheap vs 90M float atomics)
__global__ __launch_bounds__(256) void k_scatter(const int* __restrict__ src,
                                                 const int* __restrict__ dst,
                                                 unsigned* __restrict__ cursor,
                                                 unsigned* __restrict__ esrc, int E) {
  int t = blockIdx.x * 256 + threadIdx.x;
  if (t < E) {
    unsigned pos = atomicAdd(&cursor[dst[t]], 1u);
    esrc[pos] = (unsigned)src[t];
  }
}

// ---------------- hs = dinv * (x @ W1), x:[N,128] W1:[128,16] ----------------
__global__ __launch_bounds__(256) void k_gemm1(const float* __restrict__ x,
                                               const float* __restrict__ W1,
                                               const float* __restrict__ dinv,
                                               float* __restrict__ hs, int N) {
  __shared__ float xs[16][132];
  __shared__ float wT[16][132];
  int t = threadIdx.x;
#pragma unroll
  for (int i = 0; i < 8; ++i) {
    int idx = t + i * 256;
    int k = idx >> 4, c = idx & 15;
    wT[c][k] = W1[idx];
  }
  int row0 = blockIdx.x * 16;
#pragma unroll
  for (int i = 0; i < 2; ++i) {
    int idx = t + i * 256;
    int r = idx >> 5, c4 = idx & 31;
    float4 v = make_float4(0.f, 0.f, 0.f, 0.f);
    if (row0 + r < N) v = *(const float4*)(x + (size_t)(row0 + r) * N_FIN + c4 * 4);
    *(float4*)&xs[r][c4 * 4] = v;
  }
  __syncthreads();
  int col = t & 15, r = t >> 4;
  float acc = 0.f;
#pragma unroll
  for (int kc = 0; kc < 32; ++kc) {
    float4 xv = *(const float4*)&xs[r][kc * 4];
    float4 wv = *(const float4*)&wT[col][kc * 4];
    acc += xv.x * wv.x + xv.y * wv.y + xv.z * wv.z + xv.w * wv.w;
  }
  int row = row0 + r;
  if (row < N) hs[(size_t)row * N_HID + col] = dinv[row] * acc;
}

// ------ layer1 gather-aggregate + self-loop + bias + relu + 16x12 GEMM --------
// block = 16 nodes x 16 cols
__global__ __launch_bounds__(256) void k_gagg1(const unsigned* __restrict__ esrc,
                                               const unsigned* __restrict__ row_start,
                                               const unsigned* __restrict__ deg,
                                               const float* __restrict__ hs,
                                               const float* __restrict__ dinv,
                                               const float* __restrict__ b1,
                                               const float* __restrict__ W2,
                                               float* __restrict__ hs2, int N) {
  __shared__ float os[16][17];
  __shared__ float w2s[N_HID][N_OUT];
  __shared__ float b1s[N_HID];
  int t = threadIdx.x;
  if (t < N_HID * N_OUT) w2s[t / N_OUT][t % N_OUT] = W2[t];
  if (t < N_HID) b1s[t] = b1[t];
  __syncthreads();
  int nl = t >> 4, c = t & 15;
  int node = blockIdx.x * 16 + nl;
  float o = 0.f;
  if (node < N) {
    float di = dinv[node];
    unsigned s0 = row_start[node], dn = deg[node];
    float acc = 0.f;
    for (unsigned j = 0; j < dn; ++j)
      acc += hs[(size_t)esrc[s0 + j] * N_HID + c];
    o = fmaxf(di * (acc + hs[(size_t)node * N_HID + c]) + b1s[c], 0.f);
  }
  os[nl][c] = o;
  __syncthreads();
  if (t < 16 * N_OUT) {
    int n2 = t / N_OUT, c2 = t % N_OUT;
    int node2 = blockIdx.x * 16 + n2;
    if (node2 < N) {
      float s = 0.f;
#pragma unroll
      for (int cc = 0; cc < N_HID; ++cc) s += os[n2][cc] * w2s[cc][c2];
      hs2[(size_t)node2 * N_OUT + c2] = dinv[node2] * s;
    }
  }
}

// ------ layer2 gather-aggregate + self-loop + bias + log_softmax --------------
// block = 16 nodes x 12 cols = 192 threads
__global__ __launch_bounds__(192) void k_gagg2(const unsigned* __restrict__ esrc,
                                               const unsigned* __restrict__ row_start,
                                               const unsigned* __restrict__ deg,
                                               const float* __restrict__ hs2,
                                               const float* __restrict__ dinv,
                                               const float* __restrict__ b2,
                                               float* __restrict__ out, int N) {
  __shared__ float zs[16][13];
  __shared__ float b2s[N_OUT];
  int t = threadIdx.x;
  if (t < N_OUT) b2s[t] = b2[t];
  __syncthreads();
  int nl = t / N_OUT, c = t % N_OUT;
  int node = blockIdx.x * 16 + nl;
  float z = 0.f;
  if (node < N) {
    float di = dinv[node];
    unsigned s0 = row_start[node], dn = deg[node];
    float acc = 0.f;
    for (unsigned j = 0; j < dn; ++j)
      acc += hs2[(size_t)esrc[s0 + j] * N_OUT + c];
    z = di * (acc + hs2[(size_t)node * N_OUT + c]) + b2s[c];
  }
  zs[nl][c] = z;
  __syncthreads();
  if (node < N) {
    float m = zs[nl][0];
#pragma unroll
    for (int j = 1; j < N_OUT; ++j) m = fmaxf(m, zs[nl][j]);
    float sum = 0.f;
#pragma unroll
    for (int j = 0; j < N_OUT; ++j) sum += __expf(zs[nl][j] - m);
    float l = m + __logf(sum);
    out[(size_t)node * N_OUT + c] = z - l;
  }
}

extern "C" void kernel_launch(void* const* d_in, const int* in_sizes, int n_in,
                              void* d_out, int out_size, void* d_ws, size_t ws_size,
                              hipStream_t stream) {
  const float* x  = (const float*)d_in[0];
  const int*   ei = (const int*)d_in[1];
  const float* W1 = (const float*)d_in[2];
  const float* b1 = (const float*)d_in[3];
  const float* W2 = (const float*)d_in[4];
  const float* b2 = (const float*)d_in[5];
  int N = in_sizes[0] / N_FIN;
  int E = in_sizes[1] / 2;
  const int* src = ei;
  const int* dst = ei + E;
  int nb = (N + 255) / 256;

  // ws layout: [deg N][cursor N][row_start N][bsum nb(pad 1024)][dinv N][hs N*16][hs2 N*12][esrc E]
  char* ws = (char*)d_ws;
  unsigned* deg       = (unsigned*)ws;                      ws += (size_t)N * 4;
  unsigned* cursor    = (unsigned*)ws;                      ws += (size_t)N * 4;
  unsigned* row_start = (unsigned*)ws;                      ws += (size_t)N * 4;
  unsigned* bsum      = (unsigned*)ws;                      ws += 4096;
  float*    dinv      = (float*)ws;                         ws += (size_t)N * 4;
  float*    hs        = (float*)ws;                         ws += (size_t)N * N_HID * 4;
  float*    hs2       = (float*)ws;                         ws += (size_t)N * N_OUT * 4;
  unsigned* esrc      = (unsigned*)ws;

  hipMemsetAsync(deg, 0, (size_t)N * 4, stream);

  k_deg   <<<(E + 255) / 256, 256, 0, stream>>>(dst, deg, E);
  k_dinv  <<<nb, 256, 0, stream>>>(deg, dinv, N);
  k_scan1 <<<nb, 256, 0, stream>>>(deg, row_start, bsum, N);
  k_scan2 <<<1, 64, 0, stream>>>(bsum, nb);
  k_scan3 <<<nb, 256, 0, stream>>>(row_start, bsum, cursor, N);
  k_gemm1 <<<(N + 15) / 16, 256, 0, stream>>>(x, W1, dinv, hs, N);
  k_scatter<<<(E + 255) / 256, 256, 0, stream>>>(src, dst, cursor, esrc, E);
  k_gagg1 <<<(N + 15) / 16, 256, 0, stream>>>(esrc, row_start, deg, hs, dinv, b1, W2, hs2, N);
  k_gagg2 <<<(N + 15) / 16, 192, 0, stream>>>(esrc, row_start, deg, hs2, dinv, b2, (float*)d_out, N);
}